// Round 4
// baseline (142.568 us; speedup 1.0000x reference)
//
#include <hip/hip_runtime.h>

// E3Hamiltonian spin projection: fixed 4x4 complex mix over channel dim.
// [B=65536, C=8, nL*nR=169] f32, channels [r0 r1 r2 r3 | i0 i1 i2 i3].
//
// Round-4: LDS-free streaming butterflies. The mix splits into 4 independent
// 2->2 butterflies per site: u=(x+y)*s -> ch[CU], w=(x-y)*s -> ch[CW] with
// (A,B,CU,CW) = (0,2,0,3),(3,5,1,2),(4,6,4,7),(7,1,6,5).
// Each thread: 2 unaligned float4 loads + 4 VALU + 2 unaligned float4 stores
// (gfx950 supports 4B-aligned dwordx4). 169 = 4*42+1 -> chunk 42 is a scalar
// tail lane. No LDS, no barriers: same structure as the 6.3 TB/s copy bench.

#define PLANE 169
#define CSTRIDE 1352         // 8*PLANE floats per item
#define CHUNKS 43            // 42 float4 chunks + 1 scalar per (item, pair)
#define PPI 4                // butterfly pairs per item

typedef float f4u __attribute__((ext_vector_type(4), aligned(4)));

__global__ __launch_bounds__(256) void spin_proj_kernel(
    const float* __restrict__ in, float* __restrict__ out, int total) {
    int t = blockIdx.x * blockDim.x + threadIdx.x;
    if (t >= total) return;

    int n = t / (PPI * CHUNKS);          // item
    int r = t - n * (PPI * CHUNKS);
    int p = r / CHUNKS;                  // butterfly pair
    int k = r - p * CHUNKS;              // chunk within plane

    // nibble-packed LUTs (avoid runtime-indexed arrays -> scratch)
    int sh = p * 4;
    int A  = (0x7430 >> sh) & 0xF;       // input ch x: 0,3,4,7
    int B  = (0x1652 >> sh) & 0xF;       // input ch y: 2,5,6,1
    int CU = (0x6410 >> sh) & 0xF;       // out ch for (x+y)s: 0,1,4,6
    int CW = (0x5723 >> sh) & 0xF;       // out ch for (x-y)s: 3,2,7,5

    const float s = 0.70710678118654752440f;
    size_t base = (size_t)n * CSTRIDE;
    const float* __restrict__ ia = in  + base + A  * PLANE;
    const float* __restrict__ ib = in  + base + B  * PLANE;
    float* __restrict__ oa       = out + base + CU * PLANE;
    float* __restrict__ ob       = out + base + CW * PLANE;

    if (k < 42) {
        int j = 4 * k;
        f4u x = *(const f4u*)(ia + j);
        f4u y = *(const f4u*)(ib + j);
        f4u u = (x + y) * s;
        f4u w = (x - y) * s;
        *(f4u*)(oa + j) = u;
        *(f4u*)(ob + j) = w;
    } else {                              // j = 168 scalar tail
        float x = ia[168];
        float y = ib[168];
        oa[168] = (x + y) * s;
        ob[168] = (x - y) * s;
    }
}

extern "C" void kernel_launch(void* const* d_in, const int* in_sizes, int n_in,
                              void* d_out, int out_size, void* d_ws, size_t ws_size,
                              hipStream_t stream) {
    const float* in = (const float*)d_in[0];
    float* out = (float*)d_out;

    int n_items = in_sizes[0] / CSTRIDE;       // 65536
    int total = n_items * PPI * CHUNKS;        // 11,272,192 threads
    int grid = (total + 255) / 256;
    spin_proj_kernel<<<grid, 256, 0, stream>>>(in, out, total);
}

// Round 5
// 141.193 us; speedup vs baseline: 1.0097x; 1.0097x over previous
//
#include <hip/hip_runtime.h>

// E3Hamiltonian spin projection: fixed 4x4 complex mix over channel dim.
// [B=65536, C=8, nL*nR=169] f32, channels [r0 r1 r2 r3 | i0 i1 i2 i3].
//
// Round-5: round-3 wave-private LDS slab structure + grid-stride multi-item
// waves with register prefetch (async-stage split). While item t is mixed and
// drained, item t+1's 6 float4 loads are already in flight -> continuous HBM
// read stream per wave. Single slab per wave, zero s_barriers, 28 waves/CU.

#define PLANE 169
#define CSTRIDE 1352          // floats per item
#define QUADS 338             // float4 per item
#define WAVES 4               // waves per 256-thread block
#define BLOCKS 1792           // 7 blocks/CU * 256 CUs (LDS-limited occupancy)

__global__ __launch_bounds__(256) void spin_proj_kernel(
    const float4* __restrict__ in, float4* __restrict__ out,
    int n_items, int W) {
    __shared__ float lds[WAVES * CSTRIDE];   // 21632 B/block
    const int wave = threadIdx.x >> 6;
    const int lane = threadIdx.x & 63;
    float* slab = lds + wave * CSTRIDE;
    float4* slab4 = (float4*)slab;

    const int v0 = lane,        v1 = lane + 64,  v2 = lane + 128;
    const int v3 = lane + 192,  v4 = lane + 256, v5 = lane + 320;
    const bool has5 = (v5 < QUADS);          // lane < 18

    int it = blockIdx.x * WAVES + wave;
    if (it >= n_items) return;

    // Pre-load first item into registers.
    float4 p0, p1, p2, p3, p4, p5;
    {
        const float4* __restrict__ g = in + (size_t)it * QUADS;
        p0 = g[v0]; p1 = g[v1]; p2 = g[v2]; p3 = g[v3]; p4 = g[v4];
        if (has5) p5 = g[v5];
    }

    const float sc = 0.70710678118654752440f;

    while (it < n_items) {
        // Stage: regs -> LDS (coalesced b128 writes).
        slab4[v0] = p0; slab4[v1] = p1; slab4[v2] = p2;
        slab4[v3] = p3; slab4[v4] = p4;
        if (has5) slab4[v5] = p5;

        // Prefetch next item NOW -- its HBM latency hides under mix+drain.
        const int nx = it + W;
        if (nx < n_items) {
            const float4* __restrict__ g = in + (size_t)nx * QUADS;
            p0 = g[v0]; p1 = g[v1]; p2 = g[v2]; p3 = g[v3]; p4 = g[v4];
            if (has5) p5 = g[v5];
        }

        asm volatile("s_waitcnt lgkmcnt(0)" ::: "memory");  // ds_writes done
        __builtin_amdgcn_wave_barrier();

        // Mix in place; site j owned entirely by one lane (no cross-lane hazard).
        #pragma unroll
        for (int k = 0; k < 3; ++k) {
            const int j = lane + k * 64;
            if (k < 2 || j < PLANE) {
                float r0 = slab[0*PLANE + j], r1 = slab[1*PLANE + j];
                float r2 = slab[2*PLANE + j], r3 = slab[3*PLANE + j];
                float i0 = slab[4*PLANE + j], i1 = slab[5*PLANE + j];
                float i2 = slab[6*PLANE + j], i3 = slab[7*PLANE + j];
                slab[0*PLANE + j] = (r0 + r2) * sc;   // uu.re
                slab[1*PLANE + j] = (i1 + r3) * sc;   // ud.re
                slab[2*PLANE + j] = (r3 - i1) * sc;   // du.re
                slab[3*PLANE + j] = (r0 - r2) * sc;   // dd.re
                slab[4*PLANE + j] = (i0 + i2) * sc;   // uu.im
                slab[5*PLANE + j] = (i3 - r1) * sc;   // ud.im
                slab[6*PLANE + j] = (r1 + i3) * sc;   // du.im
                slab[7*PLANE + j] = (i0 - i2) * sc;   // dd.im
            }
        }

        asm volatile("s_waitcnt lgkmcnt(0)" ::: "memory");  // mix writes done
        __builtin_amdgcn_wave_barrier();

        // Drain: LDS -> global (coalesced b128). The compiler's lgkm waits for
        // the ds_read data ensure the slab is safe to overwrite next iteration.
        {
            float4* __restrict__ g = out + (size_t)it * QUADS;
            g[v0] = slab4[v0]; g[v1] = slab4[v1]; g[v2] = slab4[v2];
            g[v3] = slab4[v3]; g[v4] = slab4[v4];
            if (has5) g[v5] = slab4[v5];
        }

        it = nx;
    }
}

extern "C" void kernel_launch(void* const* d_in, const int* in_sizes, int n_in,
                              void* d_out, int out_size, void* d_ws, size_t ws_size,
                              hipStream_t stream) {
    const float4* in = (const float4*)d_in[0];
    float4* out = (float4*)d_out;

    const int n_items = in_sizes[0] / CSTRIDE;   // 65536
    int grid = BLOCKS;
    int max_grid = (n_items + WAVES - 1) / WAVES;
    if (grid > max_grid) grid = max_grid;
    const int W = grid * WAVES;                  // total waves (grid stride)

    spin_proj_kernel<<<grid, 256, 0, stream>>>(in, out, n_items, W);
}